// Round 9
// baseline (204.184 us; speedup 1.0000x reference)
//
#include <hip/hip_runtime.h>
#include <math.h>

// VQ-VAE VectorQuantizer forward for MI355X (gfx950).
// x: [B=32, C=64, H=32, W=32] f32, codebook: [K=1024, D=64] f32
// d_out (f32): quantized[2097152] | vq_loss[1] | indices[32768]
//
// Ladder: r3 TM=128 (1 wv/SIMD): 178us, VALUBusy 20%. r7 TM=32 (4 wv/SIMD):
// 87.9us, VALUBusy 45%, VGPR 44, conflicts 0 -- still wave-starved (16/32
// waves/CU, grid-limited; VGPR 44 <= 64 allows the full 32). r8: TM=16 ->
// grid 2048 = 8 blocks/CU x 4 waves = 32 waves/CU, with k re-tiled (KTILE=512,
// NPASS=2) so the per-thread inner shape (MT=4, KT=8, acc[4][8], 32 FMA per
// 3 loads per d-step) is bit-identical to r7. launch_bounds(256,8) pins
// VGPR <= 64. A from LDS (4x16B broadcast, conflict-free), B from global
// cbT[d][k] (16 distinct 32B runs/wave = 512B coalesced, L1-hot).
// fp32 FMA floor = 27.3us; x1.19 instr mix = 32.5us @ 100% VALUBusy.
// (r8 was a broker timeout -- kernel never ran; resubmitted unchanged.)
//
// Numerics (bit-exact r3/r7 -- do not touch):
//   dist = fl( fl(x2 + cb2) - 2*dot ), norms square-then-add sequential-d,
//   dot = sequential-d fma, 2*dot exact, strict-< argmin ascending k,
//   lexicographic cross-lane tie-break => jnp.argmin first-index semantics.

#define NB   32
#define ND   64
#define NHW  1024
#define NK   1024
#define TM   16          // positions per block
#define TPB  256
#define MT   4           // m per thread
#define KT   8           // k per thread
#define KTILE 512        // k per pass (64 kgroups * 8)
#define NPASS (NK / KTILE)
#define NBLK (NB * NHW / TM)     // 2048 blocks
#define QELEMS (NB * ND * NHW)   // 2097152
#define FBIG 3.402823466e38f

typedef float f4 __attribute__((ext_vector_type(4)));

// ---------- prep: codebook norms, transpose cbT[d][k], zero loss acc ----------
__global__ void vq_prep(const float* __restrict__ cb, float* __restrict__ cb2,
                        float* __restrict__ cbT, double* __restrict__ lacc) {
    int i = blockIdx.x * blockDim.x + threadIdx.x;   // 0..65535
    if (i == 0) *lacc = 0.0;
    if (i < NK) {
        float s = 0.f;
        #pragma unroll 8
        for (int d = 0; d < ND; ++d) {
            float v = cb[i * ND + d];
            s = __fadd_rn(s, __fmul_rn(v, v));       // square-then-add (sum(cb**2))
        }
        cb2[i] = s;
    }
    int d = i >> 10, k = i & 1023;
    cbT[d * NK + k] = cb[k * ND + d];
}

// ---------- main: distances + argmin + gather + STE + loss ----------
__global__ __launch_bounds__(TPB, 8)   // pin VGPR <= 64 -> 8 waves/EU capacity
void vq_main(const float* __restrict__ x, const float* __restrict__ cb,
             const float* __restrict__ cbT, const float* __restrict__ cb2g,
             float* __restrict__ outq, float* __restrict__ outidx,
             double* __restrict__ lacc)
{
    __shared__ __align__(16) float xs[ND][TM];   // 4 KB
    __shared__ float x2s[TM];
    __shared__ float wbd[4][TM];                 // per-wave best dist
    __shared__ int   wbi[4][TM];
    __shared__ int   fidx[TM];
    __shared__ float redv[4];

    const int tid = threadIdx.x;
    const int blk = blockIdx.x;
    const int b   = blk >> 6;              // 32 batches
    const int hw0 = (blk & 63) * TM;       // 64 tiles of 16 positions
    const float* xb = x + b * (ND * NHW) + hw0;

    // stage x tile (16-float = 64B runs; staging is ~2% of time)
    #pragma unroll
    for (int i = tid; i < ND * TM; i += TPB) {
        int d = i >> 4, m = i & 15;
        xs[d][m] = xb[d * NHW + m];
    }
    __syncthreads();

    // ||x||^2 per position: sequential d, square-then-add (mimic reference)
    if (tid < TM) {
        float s = 0.f;
        #pragma unroll 8
        for (int d = 0; d < ND; ++d) {
            float v = xs[d][tid];
            s = __fadd_rn(s, __fmul_rn(v, v));
        }
        x2s[tid] = s;
    }
    __syncthreads();

    const int mg = tid & 3;      // m-group: positions m0..m0+3
    const int kg = tid >> 2;     // k-group (0..63): k = pass*512 + kg*8 ..+7
    const int m0 = mg * MT;

    float x2loc[MT];
    #pragma unroll
    for (int j = 0; j < MT; ++j) x2loc[j] = x2s[m0 + j];

    float bd[MT];
    int   bi[MT];
    #pragma unroll
    for (int j = 0; j < MT; ++j) { bd[j] = FBIG; bi[j] = 0; }

    for (int pass = 0; pass < NPASS; ++pass) {
        const int k0 = pass * KTILE + kg * KT;
        float acc[MT][KT];
        #pragma unroll
        for (int j = 0; j < MT; ++j)
            #pragma unroll
            for (int jj = 0; jj < KT; ++jj) acc[j][jj] = 0.f;

        const float* bp = cbT + k0;
        #pragma unroll 2
        for (int d = 0; d < ND; ++d) {
            f4 a  = *reinterpret_cast<const f4*>(&xs[d][m0]);      // LDS broadcast
            f4 b0 = *reinterpret_cast<const f4*>(&bp[d * NK]);     // L1 pipe
            f4 b1 = *reinterpret_cast<const f4*>(&bp[d * NK + 4]);
            #pragma unroll
            for (int j = 0; j < MT; ++j) {
                float av = a[j];
                #pragma unroll
                for (int jj = 0; jj < KT; ++jj) {
                    float bv = (jj < 4) ? b0[jj & 3] : b1[jj & 3];
                    acc[j][jj] = fmaf(av, bv, acc[j][jj]);         // seq-d fma dot
                }
            }
        }

        // fold distances: dist = fl( fl(x2 + cb2) - 2*dot ), k ascending
        #pragma unroll
        for (int jj = 0; jj < KT; ++jj) {
            const int kgl = k0 + jj;
            const float c2 = cb2g[kgl];
            #pragma unroll
            for (int j = 0; j < MT; ++j) {
                float t    = __fadd_rn(x2loc[j], c2);
                float dist = __fsub_rn(t, 2.0f * acc[j][jj]);      // 2*dot exact
                if (dist < bd[j]) { bd[j] = dist; bi[j] = kgl; }   // strict <: first idx
            }
        }
    }

    // intra-wave reduce over the wave's 16 k-groups (lanes ^4..^32), lexicographic
    #pragma unroll
    for (int off = 4; off <= 32; off <<= 1) {
        #pragma unroll
        for (int j = 0; j < MT; ++j) {
            float od = __shfl_xor(bd[j], off, 64);
            int   oi = __shfl_xor(bi[j], off, 64);
            if (od < bd[j] || (od == bd[j] && oi < bi[j])) { bd[j] = od; bi[j] = oi; }
        }
    }
    const int w = tid >> 6;
    if ((tid & 63) < 4) {
        #pragma unroll
        for (int j = 0; j < MT; ++j) { wbd[w][m0 + j] = bd[j]; wbi[w][m0 + j] = bi[j]; }
    }
    __syncthreads();

    // cross-wave reduce + index write (waves cover ascending k-blocks)
    if (tid < TM) {
        float bestd = wbd[0][tid];
        int   besti = wbi[0][tid];
        #pragma unroll
        for (int t = 1; t < 4; ++t) {
            float dv = wbd[t][tid];
            int   iv = wbi[t][tid];
            if (dv < bestd || (dv == bestd && iv < besti)) { bestd = dv; besti = iv; }
        }
        fidx[tid] = besti;
        outidx[b * NHW + hw0 + tid] = (float)besti;
    }
    __syncthreads();

    // epilogue: gather codebook row, STE out = fl(x + fl(q - x)), loss accum
    const int m  = tid & 15;
    const int cq = tid >> 4;                 // channel quad: 0..15 (4 ch each)
    const int myk = fidx[m];
    const float* crow = cb + myk * ND + cq * 4;
    float* oq = outq + b * (ND * NHW) + hw0 + m;
    float ll = 0.f;
    {
        f4 v = *reinterpret_cast<const f4*>(crow);            // L2-hot gather
        #pragma unroll
        for (int j = 0; j < 4; ++j) {
            int c = cq * 4 + j;
            float xv = xs[c][m];
            float xd = __fsub_rn(v[j], xv);
            oq[c * NHW] = __fadd_rn(xv, xd);
            ll = fmaf(xd, xd, ll);
        }
    }
    #pragma unroll
    for (int off = 32; off > 0; off >>= 1) ll += __shfl_down(ll, off, 64);
    if ((tid & 63) == 0) redv[tid >> 6] = ll;
    __syncthreads();
    if (tid == 0) {
        double s = (double)redv[0] + (double)redv[1] + (double)redv[2] + (double)redv[3];
        atomicAdd(lacc, s);
    }
}

// ---------- finalize: L = mean((q-x)^2); vq_loss = L + 0.25*L ----------
// e_latent_loss == q_latent_loss numerically (same fp32 inputs/op), so
// vq_loss = L + 0.25*L with the reference's add/mul rounding.
__global__ void vq_fin(const double* __restrict__ lacc, float* __restrict__ outloss) {
    double a = *lacc;
    float L = (float)(a * (1.0 / (double)QELEMS));
    *outloss = __fadd_rn(L, __fmul_rn(0.25f, L));
}

extern "C" void kernel_launch(void* const* d_in, const int* in_sizes, int n_in,
                              void* d_out, int out_size, void* d_ws, size_t ws_size,
                              hipStream_t stream) {
    const float* x  = (const float*)d_in[0];
    const float* cb = (const float*)d_in[1];
    float* outq    = (float*)d_out;
    float* outloss = outq + QELEMS;
    float* outidx  = outq + QELEMS + 1;

    float*  cb2  = (float*)d_ws;                                  // 4 KB slot
    float*  cbT  = (float*)((char*)d_ws + 4096);                  // 256 KB
    double* lacc = (double*)((char*)d_ws + 4096 + NK * ND * 4);   // 8 B

    vq_prep<<<256, 256, 0, stream>>>(cb, cb2, cbT, lacc);
    vq_main<<<NBLK, TPB, 0, stream>>>(x, cb, cbT, cb2, outq, outidx, lacc);
    vq_fin<<<1, 1, 0, stream>>>(lacc, outloss);
}

// Round 10
// 148.517 us; speedup vs baseline: 1.3748x; 1.3748x over previous
//
#include <hip/hip_runtime.h>
#include <math.h>

// VQ-VAE VectorQuantizer forward for MI355X (gfx950).
// x: [B=32, C=64, H=32, W=32] f32, codebook: [K=1024, D=64] f32
// d_out (f32): quantized[2097152] | vq_loss[1] | indices[32768]
//
// Ladder: r3 TM=128 (grid 256): 178us, VALUBusy 20%, Occ 11% (grid-limited).
// r7 TM=32 (grid 1024, lb(256,4)): 87.9us, VALUBusy 45%, VGPR 44, Occ 39%
// -- still grid-limited (4 blocks/CU). r9 TM=16 + lb(256,8): REGRESSED 155us:
// compiler squeezed to VGPR 32 -> scratch spill (WRITE 144MB, FETCH 72MB of
// spill traffic, VALUBusy 28%). Lesson: HW packs waves by ACTUAL VGPR usage
// (44 -> 8 waves/EU fits: 8x44=352<=512); launch_bounds must only be loose
// enough to not force spills. r10: TM=16 (grid 2048 = 8 blocks/CU) +
// lb(256,4) (the no-spill config). Inner shape bit-identical to r7:
// MT=4, KT=8, acc[4][8], 32 FMA per 3 loads per d-step.
// fp32 FMA floor = 27.3us; x1.19 instr mix ~= 32.5us @ 100% VALUBusy.
//
// Numerics (bit-exact r3/r7 -- do not touch):
//   dist = fl( fl(x2 + cb2) - 2*dot ), norms square-then-add sequential-d,
//   dot = sequential-d fma, 2*dot exact, strict-< argmin ascending k,
//   lexicographic cross-lane tie-break => jnp.argmin first-index semantics.

#define NB   32
#define ND   64
#define NHW  1024
#define NK   1024
#define TM   16          // positions per block
#define TPB  256
#define MT   4           // m per thread
#define KT   8           // k per thread
#define KTILE 512        // k per pass (64 kgroups * 8)
#define NPASS (NK / KTILE)
#define NBLK (NB * NHW / TM)     // 2048 blocks
#define QELEMS (NB * ND * NHW)   // 2097152
#define FBIG 3.402823466e38f

typedef float f4 __attribute__((ext_vector_type(4)));

// ---------- prep: codebook norms, transpose cbT[d][k], zero loss acc ----------
__global__ void vq_prep(const float* __restrict__ cb, float* __restrict__ cb2,
                        float* __restrict__ cbT, double* __restrict__ lacc) {
    int i = blockIdx.x * blockDim.x + threadIdx.x;   // 0..65535
    if (i == 0) *lacc = 0.0;
    if (i < NK) {
        float s = 0.f;
        #pragma unroll 8
        for (int d = 0; d < ND; ++d) {
            float v = cb[i * ND + d];
            s = __fadd_rn(s, __fmul_rn(v, v));       // square-then-add (sum(cb**2))
        }
        cb2[i] = s;
    }
    int d = i >> 10, k = i & 1023;
    cbT[d * NK + k] = cb[k * ND + d];
}

// ---------- main: distances + argmin + gather + STE + loss ----------
__global__ __launch_bounds__(TPB, 4)   // VGPR cap 128: known-no-spill (r7: 44)
void vq_main(const float* __restrict__ x, const float* __restrict__ cb,
             const float* __restrict__ cbT, const float* __restrict__ cb2g,
             float* __restrict__ outq, float* __restrict__ outidx,
             double* __restrict__ lacc)
{
    __shared__ __align__(16) float xs[ND][TM];   // 4 KB
    __shared__ float x2s[TM];
    __shared__ float wbd[4][TM];                 // per-wave best dist
    __shared__ int   wbi[4][TM];
    __shared__ int   fidx[TM];
    __shared__ float redv[4];

    const int tid = threadIdx.x;
    const int blk = blockIdx.x;
    const int b   = blk >> 6;              // 32 batches
    const int hw0 = (blk & 63) * TM;       // 64 tiles of 16 positions
    const float* xb = x + b * (ND * NHW) + hw0;

    // stage x tile (16-float = 64B runs; staging is ~2% of time)
    #pragma unroll
    for (int i = tid; i < ND * TM; i += TPB) {
        int d = i >> 4, m = i & 15;
        xs[d][m] = xb[d * NHW + m];
    }
    __syncthreads();

    // ||x||^2 per position: sequential d, square-then-add (mimic reference)
    if (tid < TM) {
        float s = 0.f;
        #pragma unroll 8
        for (int d = 0; d < ND; ++d) {
            float v = xs[d][tid];
            s = __fadd_rn(s, __fmul_rn(v, v));
        }
        x2s[tid] = s;
    }
    __syncthreads();

    const int mg = tid & 3;      // m-group: positions m0..m0+3
    const int kg = tid >> 2;     // k-group (0..63): k = pass*512 + kg*8 ..+7
    const int m0 = mg * MT;

    float x2loc[MT];
    #pragma unroll
    for (int j = 0; j < MT; ++j) x2loc[j] = x2s[m0 + j];

    float bd[MT];
    int   bi[MT];
    #pragma unroll
    for (int j = 0; j < MT; ++j) { bd[j] = FBIG; bi[j] = 0; }

    for (int pass = 0; pass < NPASS; ++pass) {
        const int k0 = pass * KTILE + kg * KT;
        float acc[MT][KT];
        #pragma unroll
        for (int j = 0; j < MT; ++j)
            #pragma unroll
            for (int jj = 0; jj < KT; ++jj) acc[j][jj] = 0.f;

        const float* bp = cbT + k0;
        #pragma unroll 2
        for (int d = 0; d < ND; ++d) {
            f4 a  = *reinterpret_cast<const f4*>(&xs[d][m0]);      // LDS broadcast
            f4 b0 = *reinterpret_cast<const f4*>(&bp[d * NK]);     // L1/L2 pipe
            f4 b1 = *reinterpret_cast<const f4*>(&bp[d * NK + 4]);
            #pragma unroll
            for (int j = 0; j < MT; ++j) {
                float av = a[j];
                #pragma unroll
                for (int jj = 0; jj < KT; ++jj) {
                    float bv = (jj < 4) ? b0[jj & 3] : b1[jj & 3];
                    acc[j][jj] = fmaf(av, bv, acc[j][jj]);         // seq-d fma dot
                }
            }
        }

        // fold distances: dist = fl( fl(x2 + cb2) - 2*dot ), k ascending
        #pragma unroll
        for (int jj = 0; jj < KT; ++jj) {
            const int kgl = k0 + jj;
            const float c2 = cb2g[kgl];
            #pragma unroll
            for (int j = 0; j < MT; ++j) {
                float t    = __fadd_rn(x2loc[j], c2);
                float dist = __fsub_rn(t, 2.0f * acc[j][jj]);      // 2*dot exact
                if (dist < bd[j]) { bd[j] = dist; bi[j] = kgl; }   // strict <: first idx
            }
        }
    }

    // intra-wave reduce over the wave's 16 k-groups (lanes ^4..^32), lexicographic
    #pragma unroll
    for (int off = 4; off <= 32; off <<= 1) {
        #pragma unroll
        for (int j = 0; j < MT; ++j) {
            float od = __shfl_xor(bd[j], off, 64);
            int   oi = __shfl_xor(bi[j], off, 64);
            if (od < bd[j] || (od == bd[j] && oi < bi[j])) { bd[j] = od; bi[j] = oi; }
        }
    }
    const int w = tid >> 6;
    if ((tid & 63) < 4) {
        #pragma unroll
        for (int j = 0; j < MT; ++j) { wbd[w][m0 + j] = bd[j]; wbi[w][m0 + j] = bi[j]; }
    }
    __syncthreads();

    // cross-wave reduce + index write (waves cover ascending k-blocks)
    if (tid < TM) {
        float bestd = wbd[0][tid];
        int   besti = wbi[0][tid];
        #pragma unroll
        for (int t = 1; t < 4; ++t) {
            float dv = wbd[t][tid];
            int   iv = wbi[t][tid];
            if (dv < bestd || (dv == bestd && iv < besti)) { bestd = dv; besti = iv; }
        }
        fidx[tid] = besti;
        outidx[b * NHW + hw0 + tid] = (float)besti;
    }
    __syncthreads();

    // epilogue: gather codebook row, STE out = fl(x + fl(q - x)), loss accum
    const int m  = tid & 15;
    const int cq = tid >> 4;                 // channel quad: 0..15 (4 ch each)
    const int myk = fidx[m];
    const float* crow = cb + myk * ND + cq * 4;
    float* oq = outq + b * (ND * NHW) + hw0 + m;
    float ll = 0.f;
    {
        f4 v = *reinterpret_cast<const f4*>(crow);            // L2-hot gather
        #pragma unroll
        for (int j = 0; j < 4; ++j) {
            int c = cq * 4 + j;
            float xv = xs[c][m];
            float xd = __fsub_rn(v[j], xv);
            oq[c * NHW] = __fadd_rn(xv, xd);
            ll = fmaf(xd, xd, ll);
        }
    }
    #pragma unroll
    for (int off = 32; off > 0; off >>= 1) ll += __shfl_down(ll, off, 64);
    if ((tid & 63) == 0) redv[tid >> 6] = ll;
    __syncthreads();
    if (tid == 0) {
        double s = (double)redv[0] + (double)redv[1] + (double)redv[2] + (double)redv[3];
        atomicAdd(lacc, s);
    }
}

// ---------- finalize: L = mean((q-x)^2); vq_loss = L + 0.25*L ----------
// e_latent_loss == q_latent_loss numerically (same fp32 inputs/op), so
// vq_loss = L + 0.25*L with the reference's add/mul rounding.
__global__ void vq_fin(const double* __restrict__ lacc, float* __restrict__ outloss) {
    double a = *lacc;
    float L = (float)(a * (1.0 / (double)QELEMS));
    *outloss = __fadd_rn(L, __fmul_rn(0.25f, L));
}

extern "C" void kernel_launch(void* const* d_in, const int* in_sizes, int n_in,
                              void* d_out, int out_size, void* d_ws, size_t ws_size,
                              hipStream_t stream) {
    const float* x  = (const float*)d_in[0];
    const float* cb = (const float*)d_in[1];
    float* outq    = (float*)d_out;
    float* outloss = outq + QELEMS;
    float* outidx  = outq + QELEMS + 1;

    float*  cb2  = (float*)d_ws;                                  // 4 KB slot
    float*  cbT  = (float*)((char*)d_ws + 4096);                  // 256 KB
    double* lacc = (double*)((char*)d_ws + 4096 + NK * ND * 4);   // 8 B

    vq_prep<<<256, 256, 0, stream>>>(cb, cb2, cbT, lacc);
    vq_main<<<NBLK, TPB, 0, stream>>>(x, cb, cbT, cb2, outq, outidx, lacc);
    vq_fin<<<1, 1, 0, stream>>>(lacc, outloss);
}